// Round 10
// baseline (241.847 us; speedup 1.0000x reference)
//
#include <hip/hip_runtime.h>
#include <math.h>

// ---------- constants ----------
// B=4 T=1024 E=768 H=12 HD=64, NUM_BUCKETS=320, MAX_DIST=800
#define TT 1024
#define EE 768
#define HH 12

typedef __attribute__((ext_vector_type(8))) __bf16 bf16x8;
typedef __attribute__((ext_vector_type(4))) float f32x4;

__device__ __forceinline__ unsigned short f2b(float f) {
    unsigned int u = __float_as_uint(f);
    unsigned int r = (u + 0x7fffu + ((u >> 16) & 1u)) >> 16;
    return (unsigned short)r;
}

// async global->LDS, 16 bytes per lane; LDS dst must be wave-uniform base + lane*16
#define GLD16(gsrc, ldst) \
    __builtin_amdgcn_global_load_lds( \
        (const __attribute__((address_space(1))) unsigned int*)(gsrc), \
        (__attribute__((address_space(3))) unsigned int*)(ldst), 16, 0, 0)

// ---------- conv: convert hs + 4 weights fp32 -> bf16 (r4-proven prep_k, 0 LDS) ----------
__global__ __launch_bounds__(256)
void conv_k(const float* __restrict__ hs, const float* __restrict__ Wq,
            const float* __restrict__ Wk, const float* __restrict__ Wv,
            const float* __restrict__ Wo, unsigned short* __restrict__ out) {
    size_t i = 4 * (size_t)(blockIdx.x * 256 + threadIdx.x);
    if (i >= 5505024) return;
    const float* src;
    if (i < 3145728)      src = hs + i;
    else if (i < 3735552) src = Wq + (i - 3145728);
    else if (i < 4325376) src = Wk + (i - 3735552);
    else if (i < 4915200) src = Wv + (i - 4325376);
    else                  src = Wo + (i - 4915200);
    float4 f = *(const float4*)src;
    unsigned int lo = (unsigned int)f2b(f.x) | ((unsigned int)f2b(f.y) << 16);
    unsigned int hi = (unsigned int)f2b(f.z) | ((unsigned int)f2b(f.w) << 16);
    uint2 p; p.x = lo; p.y = hi;
    *(uint2*)&out[i] = p;
}

// ---------- wT2: W^T transpose [0,108) + biasTab [108,204) + bias2/B2 [204,216) ----------
__global__ __launch_bounds__(256)
void wT2_k(const float* __restrict__ Wq, const float* __restrict__ Wk,
           const float* __restrict__ Wv,
           const float* __restrict__ bq, const float* __restrict__ bk,
           const float* __restrict__ bv,
           const float* __restrict__ Bq, const float* __restrict__ Bk,
           const float* __restrict__ Bv, const float* __restrict__ rel,
           unsigned short* __restrict__ WT_all, float* __restrict__ biasTab,
           float* __restrict__ bias2, float* __restrict__ B2) {
    __shared__ __align__(16) char smem[34816];
    const int bid = blockIdx.x, tid = threadIdx.x;
    if (bid < 108) {                        // ---- W^T (padded LDS, r7/r9-proven) ----
        unsigned short* Ts = (unsigned short*)smem;   // [128][136]
        int mat = bid / 36, tile = bid % 36;
        int tr = tile / 6, tc = tile % 6;
        const float* S = mat == 0 ? Wq : (mat == 1 ? Wk : Wv);
        #pragma unroll
        for (int i = 0; i < 16; ++i) {
            int idx = i * 256 + tid;
            int row = idx >> 5, col4 = (idx & 31) * 4;
            float4 f = *(const float4*)&S[(size_t)(tr * 128 + row) * EE + tc * 128 + col4];
            Ts[(col4 + 0) * 136 + row] = f2b(f.x);
            Ts[(col4 + 1) * 136 + row] = f2b(f.y);
            Ts[(col4 + 2) * 136 + row] = f2b(f.z);
            Ts[(col4 + 3) * 136 + row] = f2b(f.w);
        }
        __syncthreads();
        unsigned short* dst = WT_all + (size_t)mat * 589824;
        #pragma unroll
        for (int i = 0; i < 8; ++i) {
            int idx = i * 256 + tid;
            int rr = idx >> 4, cg = (idx & 15) * 8;
            *(uint4*)&dst[(size_t)(tc * 128 + rr) * EE + tr * 128 + cg] =
                *(const uint4*)&Ts[rr * 136 + cg];
        }
    } else if (bid < 204) {                 // ---- biasTab ----
        int idx = (bid - 108) * 256 + tid;
        if (idx < 2047 * 12) {
            int h = idx % 12;
            int rr = idx / 12;
            int relv = rr - 1023;
            int base = relv > 0 ? 160 : 0;
            int ar = relv < 0 ? -relv : relv;
            int bkt;
            if (ar < 80) bkt = base + ar;
            else {
                double lr = log((double)ar / 80.0);
                int large = 80 + (int)(lr / log(10.0) * 80.0);
                if (large > 159) large = 159;
                bkt = base + large;
            }
            biasTab[h * 2048 + rr] = rel[bkt * 12 + h];
        }
    } else {                                // ---- bias2 / B2 (q pre-scaled 0.125) ----
        float* bvS = (float*)smem;           // 768
        float* BmS = bvS + 768;              // 1536
        int v = bid - 204;                   // 0..11
        int sel = v / 4, nb = (v % 4) * 192;
        const float* W = sel == 0 ? Wq : (sel == 1 ? Wk : Wv);
        const float* bvec = sel == 0 ? bq : (sel == 1 ? bk : bv);
        const float* Bm = sel == 0 ? Bq : (sel == 1 ? Bk : Bv);
        for (int i = tid; i < 768; i += 256) bvS[i] = bvec[i];
        for (int i = tid; i < 1536; i += 256) BmS[i] = Bm[i];
        __syncthreads();
        if (tid < 192) {
            int n = nb + tid;
            const float* Wrow = W + (size_t)n * EE;
            float a0 = 0.f, a1 = 0.f, a2 = 0.f;
            for (int o = 0; o < EE; o += 4) {
                float4 w = *(const float4*)&Wrow[o];
                a0 += w.x * bvS[o] + w.y * bvS[o + 1] + w.z * bvS[o + 2] + w.w * bvS[o + 3];
                a1 += w.x * BmS[o * 2] + w.y * BmS[o * 2 + 2] + w.z * BmS[o * 2 + 4] + w.w * BmS[o * 2 + 6];
                a2 += w.x * BmS[o * 2 + 1] + w.y * BmS[o * 2 + 3] + w.z * BmS[o * 2 + 5] + w.w * BmS[o * 2 + 7];
            }
            float sc = (sel == 0) ? 0.125f : 1.0f;
            bias2[sel * 768 + n] = (a0 + bvS[n]) * sc;
            B2[sel * 1536 + n * 2 + 0] = a1 * sc;
            B2[sel * 1536 + n * 2 + 1] = a2 * sc;
        }
    }
}

// ---------- hs_k: gates + lora, 8 rows/block, 512 blocks (49.4 KB LDS -> 3/CU) ----------
__global__ __launch_bounds__(256)
void hs_k(const float* __restrict__ hs, const float* __restrict__ Wg,
          const float* __restrict__ bg, const float* __restrict__ gru,
          const float* __restrict__ Aq, const float* __restrict__ Ak,
          const float* __restrict__ Av,
          float* __restrict__ gate, float* __restrict__ xA) {
    __shared__ float rowF[8 * 772];
    __shared__ float AS[6 * 768];
    __shared__ float WgS[8 * 68];
    __shared__ float gpS[8 * 100];
    __shared__ float redS[4 * 48];
    __shared__ float bgS[8];
    __shared__ float gcS[12];
    const int tid = threadIdx.x;
    const int m0 = blockIdx.x * 8;

    for (int i = tid; i < 512; i += 256) WgS[(i >> 6) * 68 + (i & 63)] = Wg[i];
    for (int i = tid; i < 1152; i += 256) {
        int which = i / 192, c4 = (i % 192) * 4;
        const float* src = (which < 2 ? Aq : (which < 4 ? Ak : Av)) + (which & 1) * 768 + c4;
        float4 f = *(const float4*)src;
        AS[which * 768 + c4 + 0] = f.x; AS[which * 768 + c4 + 1] = f.y;
        AS[which * 768 + c4 + 2] = f.z; AS[which * 768 + c4 + 3] = f.w;
    }
    if (tid < 8)  bgS[tid] = bg[tid];
    if (tid < 12) gcS[tid] = gru[tid];
    #pragma unroll
    for (int i = 0; i < 6; ++i) {
        int idx = i * 256 + tid;                 // [0,1536)
        int row = idx / 192, c4 = (idx % 192) * 4;
        float4 f = *(const float4*)&hs[(size_t)(m0 + row) * EE + c4];
        rowF[row * 772 + c4 + 0] = f.x; rowF[row * 772 + c4 + 1] = f.y;
        rowF[row * 772 + c4 + 2] = f.z; rowF[row * 772 + c4 + 3] = f.w;
    }
    __syncthreads();
    // gates partial dots: 8 rows x 96 (h,e)
    #pragma unroll
    for (int j = 0; j < 3; ++j) {
        int idx = j * 256 + tid;                 // [0,768)
        int row = idx & 7, q = idx >> 3;
        int h = q % 12, e = q / 12;
        const float* rp = &rowF[row * 772 + h * 64];
        const float* wp = &WgS[e * 68];
        float a = 0.f;
        #pragma unroll 16
        for (int d = 0; d < 64; ++d) a += rp[d] * wp[d];
        gpS[row * 100 + h * 8 + e] = a;
    }
    // lora partials: row = tid&7, seg = tid>>3 (32 segs of 24)
    {
        int row = tid & 7, seg = tid >> 3;
        float s[6] = {0.f, 0.f, 0.f, 0.f, 0.f, 0.f};
        #pragma unroll 8
        for (int j = 0; j < 24; ++j) {
            int e = seg * 24 + j;
            float xv = rowF[row * 772 + e];
            s[0] += xv * AS[e];            s[1] += xv * AS[768 + e];
            s[2] += xv * AS[1536 + e];     s[3] += xv * AS[2304 + e];
            s[4] += xv * AS[3072 + e];     s[5] += xv * AS[3840 + e];
        }
        #pragma unroll
        for (int i = 0; i < 6; ++i) {
            s[i] += __shfl_xor(s[i], 8, 64);
            s[i] += __shfl_xor(s[i], 16, 64);
            s[i] += __shfl_xor(s[i], 32, 64);
        }
        int lane = tid & 63, w = tid >> 6;
        if ((lane >> 3) == 0)
            #pragma unroll
            for (int i = 0; i < 6; ++i) redS[w * 48 + row * 6 + i] = s[i];
    }
    __syncthreads();
    if (tid < 48) {
        int row = tid / 6, i = tid % 6;
        float v = redS[row * 6 + i] + redS[48 + row * 6 + i] +
                  redS[96 + row * 6 + i] + redS[144 + row * 6 + i];
        int sel = i >> 1, r = i & 1;
        xA[sel * 8192 + (size_t)(m0 + row) * 2 + r] = v;
    }
    if (tid < 96) {
        int row = tid / 12, h = tid % 12;
        const float* gp = &gpS[row * 100 + h * 8];
        float s0 = gp[0] + gp[1] + gp[2] + gp[3] + bgS[0] + bgS[1] + bgS[2] + bgS[3];
        float s1 = gp[4] + gp[5] + gp[6] + gp[7] + bgS[4] + bgS[5] + bgS[6] + bgS[7];
        float ga = 1.f / (1.f + __expf(-s0));
        float gb = 1.f / (1.f + __expf(-s1));
        int m = m0 + row;
        int b = m >> 10, tp = m & 1023;
        gate[((size_t)b * HH + h) * TT + tp] = ga * (gb * gcS[h] - 1.0f) + 2.0f;
    }
}

// ---------- W2 = W@W (bf16), 64x128 tiles, 216 blocks; q pre-scaled 0.125 ----------
__global__ __launch_bounds__(256, 4)
void wgemm_k(const unsigned short* __restrict__ Wall_b,
             const unsigned short* __restrict__ WT_all,
             unsigned short* __restrict__ W2_all) {
    __shared__ unsigned short At[64 * 32];
    __shared__ unsigned short Bt[128 * 32];
    const int tid = threadIdx.x;
    const int sel = blockIdx.x / 72, tile = blockIdx.x % 72;
    const int row0 = (tile / 6) * 64, col0 = (tile % 6) * 128;
    const unsigned short* A = Wall_b + (size_t)sel * 589824;
    const unsigned short* Bw = WT_all + (size_t)sel * 589824;

    const int lane = tid & 63, wv = tid >> 6;
    const int wm = (wv & 1) * 32, wn = (wv >> 1) * 64;
    const int l15 = lane & 15, g8 = (lane >> 4) * 8;
    const int lr = lane >> 2, lc = (lane & 3) * 8;
    const int c0 = wv * 2, c1 = wv * 2 + 1;
    const unsigned short* Abase  = A + (size_t)(row0 + wv * 16 + lr) * EE + lc;
    const unsigned short* Bbase0 = Bw + (size_t)(col0 + c0 * 16 + lr) * EE + lc;
    const unsigned short* Bbase1 = Bw + (size_t)(col0 + c1 * 16 + lr) * EE + lc;

    f32x4 zero4 = {0.f, 0.f, 0.f, 0.f};
    f32x4 acc[2][4];
    #pragma unroll
    for (int i = 0; i < 2; ++i)
        #pragma unroll
        for (int j = 0; j < 4; ++j) acc[i][j] = zero4;

    for (int kt = 0; kt < 768; kt += 32) {
        GLD16(Abase + kt, &At[wv * 512]);
        GLD16(Bbase0 + kt, &Bt[c0 * 512]);
        GLD16(Bbase1 + kt, &Bt[c1 * 512]);
        __syncthreads();
        bf16x8 af[2], bf[4];
        #pragma unroll
        for (int mt = 0; mt < 2; ++mt) af[mt] = *(const bf16x8*)&At[(wm + mt * 16 + l15) * 32 + g8];
        #pragma unroll
        for (int nt = 0; nt < 4; ++nt) bf[nt] = *(const bf16x8*)&Bt[(wn + nt * 16 + l15) * 32 + g8];
        #pragma unroll
        for (int mt = 0; mt < 2; ++mt)
            #pragma unroll
            for (int nt = 0; nt < 4; ++nt)
                acc[mt][nt] = __builtin_amdgcn_mfma_f32_16x16x32_bf16(af[mt], bf[nt], acc[mt][nt], 0, 0, 0);
        __syncthreads();
    }
    unsigned short* out = W2_all + (size_t)sel * 589824;
    const float sc = (sel == 0) ? 0.125f : 1.0f;
    const int g4 = (lane >> 4) * 4;
    #pragma unroll
    for (int mt = 0; mt < 2; ++mt)
        #pragma unroll
        for (int r = 0; r < 4; ++r) {
            int grow = row0 + wm + mt * 16 + g4 + r;
            #pragma unroll
            for (int nt = 0; nt < 4; ++nt) {
                int ncol = col0 + wn + nt * 16 + l15;
                out[(size_t)grow * EE + ncol] = f2b(acc[mt][nt][r] * sc);
            }
        }
}

// ---------- fused QKV GEMM: 64x128 tiles, grid (18,64), 4 blocks/CU ----------
__global__ __launch_bounds__(256, 4)
void qkv_gemm_k(const unsigned short* __restrict__ Aall,
                const unsigned short* __restrict__ W2_all,
                const float* __restrict__ bias2,
                const float* __restrict__ xA, const float* __restrict__ B2,
                unsigned short* __restrict__ qb, unsigned short* __restrict__ kb,
                unsigned short* __restrict__ vb) {
    __shared__ unsigned short At[64 * 32];
    __shared__ unsigned short Bt[128 * 32];
    const int tid = threadIdx.x;
    const int bx = blockIdx.x, by = blockIdx.y;
    const int sel = bx / 6;
    const int col0 = (bx % 6) * 128, row0 = by * 64;
    const unsigned short* Wb = W2_all + (size_t)sel * 589824;
    const float* bias = bias2 + sel * 768;

    const int lane = tid & 63, wv = tid >> 6;
    const int wm = (wv & 1) * 32, wn = (wv >> 1) * 64;
    const int l15 = lane & 15, g8 = (lane >> 4) * 8;
    const int lr = lane >> 2, lc = (lane & 3) * 8;
    const int c0 = wv * 2, c1 = wv * 2 + 1;
    const unsigned short* Abase  = Aall + (size_t)(row0 + wv * 16 + lr) * EE + lc;
    const unsigned short* Bbase0 = Wb + (size_t)(col0 + c0 * 16 + lr) * EE + lc;
    const unsigned short* Bbase1 = Wb + (size_t)(col0 + c1 * 16 + lr) * EE + lc;

    f32x4 zero4 = {0.f, 0.f, 0.f, 0.f};
    f32x4 acc[2][4];
    #pragma unroll
    for (int i = 0; i < 2; ++i)
        #pragma unroll
        for (int j = 0; j < 4; ++j) acc[i][j] = zero4;

    for (int kt = 0; kt < 768; kt += 32) {
        GLD16(Abase + kt, &At[wv * 512]);
        GLD16(Bbase0 + kt, &Bt[c0 * 512]);
        GLD16(Bbase1 + kt, &Bt[c1 * 512]);
        __syncthreads();
        bf16x8 af[2], bf[4];
        #pragma unroll
        for (int mt = 0; mt < 2; ++mt) af[mt] = *(const bf16x8*)&At[(wm + mt * 16 + l15) * 32 + g8];
        #pragma unroll
        for (int nt = 0; nt < 4; ++nt) bf[nt] = *(const bf16x8*)&Bt[(wn + nt * 16 + l15) * 32 + g8];
        #pragma unroll
        for (int mt = 0; mt < 2; ++mt)
            #pragma unroll
            for (int nt = 0; nt < 4; ++nt)
                acc[mt][nt] = __builtin_amdgcn_mfma_f32_16x16x32_bf16(af[mt], bf[nt], acc[mt][nt], 0, 0, 0);
        __syncthreads();
    }

    unsigned short* dst = sel == 0 ? qb : (sel == 1 ? kb : vb);
    const float* Lbase = xA + sel * 8192;
    const float* B2s   = B2 + sel * 1536;
    const int g4 = (lane >> 4) * 4;
    #pragma unroll
    for (int mt = 0; mt < 2; ++mt) {
        #pragma unroll
        for (int r = 0; r < 4; ++r) {
            size_t grow = (size_t)row0 + wm + mt * 16 + g4 + r;
            float l0 = Lbase[grow * 2], l1 = Lbase[grow * 2 + 1];
            #pragma unroll
            for (int nt = 0; nt < 4; ++nt) {
                int ncol = col0 + wn + nt * 16 + l15;
                float c = acc[mt][nt][r] + bias[ncol]
                          + 0.5f * (l0 * B2s[ncol * 2] + l1 * B2s[ncol * 2 + 1]);
                dst[grow * EE + ncol] = f2b(c);
            }
        }
    }
}

// ---------- V transpose (r4-proven) ----------
__global__ __launch_bounds__(256)
void vT_k(const unsigned short* __restrict__ vb, unsigned short* __restrict__ Vtg) {
    __shared__ unsigned short Vs[64 * 72];
    const int tid = threadIdx.x;
    const int tt = blockIdx.x, h = blockIdx.y, b = blockIdx.z;
    const int r = tid >> 3, cc = (tid & 7) * 8;
    #pragma unroll
    for (int i = 0; i < 2; ++i) {
        int row = i * 32 + r;
        const unsigned short* vp = vb + (size_t)(b * TT + tt * 64 + row) * EE + h * 64 + cc;
        *(uint4*)&Vs[row * 72 + cc] = *(const uint4*)vp;
    }
    __syncthreads();
    #pragma unroll
    for (int i = 0; i < 2; ++i) {
        int d = i * 32 + r;
        unsigned short tmp[8] __attribute__((aligned(16)));
        #pragma unroll
        for (int j = 0; j < 8; ++j) tmp[j] = Vs[(cc + j) * 72 + d];
        *(uint4*)&Vtg[((size_t)(b * HH + h) * 64 + d) * TT + tt * 64 + cc] = *(const uint4*)tmp;
    }
}

// ---------- MFMA flash attention (r9-proven): bias via L2, K/V prefetch, 4 blocks/CU ----------
__global__ __launch_bounds__(256, 4)
void attn_k(const unsigned short* __restrict__ qb, const unsigned short* __restrict__ kb,
            const unsigned short* __restrict__ Vtg, const float* __restrict__ gate,
            const float* __restrict__ biasTab, unsigned short* __restrict__ ctx) {
    __shared__ unsigned short Qs[64 * 72];
    __shared__ unsigned short Ks[64 * 72];
    __shared__ unsigned short Vt[64 * 72];
    __shared__ unsigned short Ps[64 * 72];
    const int tid = threadIdx.x;
    const int qt = blockIdx.x, h = blockIdx.y, b = blockIdx.z;

    const int srow = tid >> 2, scol = (tid & 3) * 16;
    {
        const unsigned short* qp = qb + ((size_t)(b * TT + qt * 64 + srow)) * EE + h * 64 + scol;
        *(uint4*)&Qs[srow * 72 + scol]     = *(const uint4*)qp;
        *(uint4*)&Qs[srow * 72 + scol + 8] = *(const uint4*)(qp + 8);
    }
    const int lane = tid & 63, wv = tid >> 6;
    const int m0 = wv * 16;
    const int l15 = lane & 15, g = lane >> 4;

    float li[4];
    f32x4 zero4 = {0.f, 0.f, 0.f, 0.f};
    f32x4 oa[4];
    #pragma unroll
    for (int r = 0; r < 4; ++r) li[r] = 0.f;
    #pragma unroll
    for (int nt = 0; nt < 4; ++nt) oa[nt] = zero4;
    float gv[4];
    #pragma unroll
    for (int r = 0; r < 4; ++r)
        gv[r] = gate[((size_t)(b * HH + h)) * TT + qt * 64 + m0 + 4 * g + r];

    const unsigned short* kpbase = kb + ((size_t)(b * TT + srow)) * EE + h * 64 + scol;
    const unsigned short* vpbase = Vtg + ((size_t)(b * HH + h) * 64 + srow) * TT + scol;
    const float* btab = biasTab + h * 2048 + 1023 + l15 - qt * 64 - m0 - 4 * g;

    uint4 kr0 = *(const uint4*)kpbase;
    uint4 kr1 = *(const uint4*)(kpbase + 8);
    uint4 vr0 = *(const uint4*)vpbase;
    uint4 vr1 = *(const uint4*)(vpbase + 8);

    for (int kt = 0; kt < 16; ++kt) {
        __syncthreads();
        *(uint4*)&Ks[srow * 72 + scol]     = kr0;
        *(uint4*)&Ks[srow * 72 + scol + 8] = kr1;
        *(uint4*)&Vt[srow * 72 + scol]     = vr0;
        *(uint4*)&Vt[srow * 72 + scol + 8] = vr1;
        __syncthreads();
        if (kt < 15) {
            const unsigned short* kp = kpbase + (size_t)(kt + 1) * 64 * EE;
            kr0 = *(const uint4*)kp;
            kr1 = *(const uint4*)(kp + 8);
            const unsigned short* vp = vpbase + (kt + 1) * 64;
            vr0 = *(const uint4*)vp;
            vr1 = *(const uint4*)(vp + 8);
        }
        f32x4 sa[4];
        #pragma unroll
        for (int nt = 0; nt < 4; ++nt) sa[nt] = zero4;
        bf16x8 aq0 = *(const bf16x8*)&Qs[(m0 + l15) * 72 + g * 8];
        bf16x8 aq1 = *(const bf16x8*)&Qs[(m0 + l15) * 72 + 32 + g * 8];
        #pragma unroll
        for (int nt = 0; nt < 4; ++nt) {
            bf16x8 bk0 = *(const bf16x8*)&Ks[(nt * 16 + l15) * 72 + g * 8];
            bf16x8 bk1 = *(const bf16x8*)&Ks[(nt * 16 + l15) * 72 + 32 + g * 8];
            sa[nt] = __builtin_amdgcn_mfma_f32_16x16x32_bf16(aq0, bk0, sa[nt], 0, 0, 0);
            sa[nt] = __builtin_amdgcn_mfma_f32_16x16x32_bf16(aq1, bk1, sa[nt], 0, 0, 0);
        }
        #pragma unroll
        for (int nt = 0; nt < 4; ++nt) {
            const float* bt = btab + kt * 64 + nt * 16;
            #pragma unroll
            for (int r = 0; r < 4; ++r) {
                float e = __expf(fmaf(gv[r], bt[-r], sa[nt][r]));
                li[r] += e;
                Ps[(m0 + 4 * g + r) * 72 + nt * 16 + l15] = f2b(e);
            }
        }
        bf16x8 ap0 = *(const bf16x8*)&Ps[(m0 + l15) * 72 + g * 8];
        bf16x8 ap1 = *(const bf16x8*)&Ps[(m0 + l15) * 72 + 32 + g * 8];
        #pragma unroll
        for (int nt = 0; nt < 4; ++nt) {
            bf16x8 bv0 = *(const bf16x8*)&Vt[(nt * 16 + l15) * 72 + g * 8];
            bf16x8 bv1 = *(const bf16x8*)&Vt[(nt * 16 + l15) * 72 + 32 + g * 8];
            oa[nt] = __builtin_amdgcn_mfma_f32_16x16x32_bf16(ap0, bv0, oa[nt], 0, 0, 0);
            oa[nt] = __builtin_amdgcn_mfma_f32_16x16x32_bf16(ap1, bv1, oa[nt], 0, 0, 0);
        }
    }
    __syncthreads();
    #pragma unroll
    for (int r = 0; r < 4; ++r) {
        #pragma unroll
        for (int msk = 1; msk < 16; msk <<= 1)
            li[r] += __shfl_xor(li[r], msk, 16);
    }
    #pragma unroll
    for (int nt = 0; nt < 4; ++nt)
        #pragma unroll
        for (int r = 0; r < 4; ++r)
            Ks[(m0 + 4 * g + r) * 72 + nt * 16 + l15] = f2b(oa[nt][r] / li[r]);
    __syncthreads();
    {
        unsigned short* cp = ctx + ((size_t)(b * TT + qt * 64 + srow)) * EE + h * 64 + scol;
        *(uint4*)cp       = *(const uint4*)&Ks[srow * 72 + scol];
        *(uint4*)(cp + 8) = *(const uint4*)&Ks[srow * 72 + scol + 8];
    }
}

// ---------- output GEMM (r9-proven): 64x128 tiles, grid 384 ----------
__global__ __launch_bounds__(256, 4)
void out_gemm_k(const unsigned short* __restrict__ Aall,
                const unsigned short* __restrict__ Wob,
                const float* __restrict__ bo, float* __restrict__ outf) {
    __shared__ unsigned short At[64 * 32];
    __shared__ unsigned short Bt[128 * 32];
    const int tid = threadIdx.x;
    const int col0 = blockIdx.x * 128, row0 = blockIdx.y * 64;

    const int lane = tid & 63, wv = tid >> 6;
    const int wm = (wv & 1) * 32, wn = (wv >> 1) * 64;
    const int l15 = lane & 15, g8 = (lane >> 4) * 8;
    const int lr = lane >> 2, lc = (lane & 3) * 8;
    const int c0 = wv * 2, c1 = wv * 2 + 1;
    const unsigned short* Abase  = Aall + (size_t)(row0 + wv * 16 + lr) * EE + lc;
    const unsigned short* Bbase0 = Wob + (size_t)(col0 + c0 * 16 + lr) * EE + lc;
    const unsigned short* Bbase1 = Wob + (size_t)(col0 + c1 * 16 + lr) * EE + lc;

    f32x4 zero4 = {0.f, 0.f, 0.f, 0.f};
    f32x4 acc[2][4];
    #pragma unroll
    for (int i = 0; i < 2; ++i)
        #pragma unroll
        for (int j = 0; j < 4; ++j) acc[i][j] = zero4;

    for (int kt = 0; kt < 768; kt += 32) {
        GLD16(Abase + kt, &At[wv * 512]);
        GLD16(Bbase0 + kt, &Bt[c0 * 512]);
        GLD16(Bbase1 + kt, &Bt[c1 * 512]);
        __syncthreads();
        bf16x8 af[2], bf[4];
        #pragma unroll
        for (int mt = 0; mt < 2; ++mt) af[mt] = *(const bf16x8*)&At[(wm + mt * 16 + l15) * 32 + g8];
        #pragma unroll
        for (int nt = 0; nt < 4; ++nt) bf[nt] = *(const bf16x8*)&Bt[(wn + nt * 16 + l15) * 32 + g8];
        #pragma unroll
        for (int mt = 0; mt < 2; ++mt)
            #pragma unroll
            for (int nt = 0; nt < 4; ++nt)
                acc[mt][nt] = __builtin_amdgcn_mfma_f32_16x16x32_bf16(af[mt], bf[nt], acc[mt][nt], 0, 0, 0);
        __syncthreads();
    }
    const int g4 = (lane >> 4) * 4;
    #pragma unroll
    for (int mt = 0; mt < 2; ++mt)
        #pragma unroll
        for (int r = 0; r < 4; ++r) {
            size_t grow = (size_t)row0 + wm + mt * 16 + g4 + r;
            #pragma unroll
            for (int nt = 0; nt < 4; ++nt) {
                int ncol = col0 + wn + nt * 16 + l15;
                outf[grow * EE + ncol] = acc[mt][nt][r] + bo[ncol];
            }
        }
}

// ---------- launch ----------
extern "C" void kernel_launch(void* const* d_in, const int* in_sizes, int n_in,
                              void* d_out, int out_size, void* d_ws, size_t ws_size,
                              hipStream_t stream) {
    const float* hs  = (const float*)d_in[0];
    const float* Wq  = (const float*)d_in[1];
    const float* bq  = (const float*)d_in[2];
    const float* Wk  = (const float*)d_in[3];
    const float* bk  = (const float*)d_in[4];
    const float* Wv  = (const float*)d_in[5];
    const float* bv  = (const float*)d_in[6];
    const float* Aq  = (const float*)d_in[7];
    const float* Bq  = (const float*)d_in[8];
    const float* Ak  = (const float*)d_in[9];
    const float* Bk  = (const float*)d_in[10];
    const float* Av  = (const float*)d_in[11];
    const float* Bv  = (const float*)d_in[12];
    const float* Wo  = (const float*)d_in[13];
    const float* bo  = (const float*)d_in[14];
    const float* Wg  = (const float*)d_in[15];
    const float* bg  = (const float*)d_in[16];
    const float* gru = (const float*)d_in[17];
    const float* rel = (const float*)d_in[18];

    float* ws = (float*)d_ws;
    float* gate    = ws;                    // 49152
    float* biasTab = gate + 49152;          // 24576
    float* xA      = biasTab + 24576;       // 24576
    float* bias2   = xA + 24576;            // 2304
    float* B2      = bias2 + 2304;          // 4608
    unsigned short* hsb    = (unsigned short*)(B2 + 4608);
    unsigned short* Wall_b = hsb + 3145728;          // 4 x 589824 (Wq,Wk,Wv,Wo)
    unsigned short* WT_all = Wall_b + 4 * 589824;    // 3 x 589824
    unsigned short* W2_all = WT_all + 3 * 589824;    // 3 x 589824
    unsigned short* qb     = W2_all + 3 * 589824;
    unsigned short* kb     = qb + 3145728;
    unsigned short* vb     = kb + 3145728;
    unsigned short* Vtg    = vb + 3145728;
    unsigned short* ctxb   = Vtg + 3145728;

    conv_k<<<5376, 256, 0, stream>>>(hs, Wq, Wk, Wv, Wo, hsb);
    wT2_k<<<216, 256, 0, stream>>>(Wq, Wk, Wv, bq, bk, bv, Bq, Bk, Bv, rel,
                                   WT_all, biasTab, bias2, B2);
    hs_k<<<512, 256, 0, stream>>>(hs, Wg, bg, gru, Aq, Ak, Av, gate, xA);
    wgemm_k<<<216, 256, 0, stream>>>(Wall_b, WT_all, W2_all);
    qkv_gemm_k<<<dim3(18, 64), 256, 0, stream>>>(hsb, W2_all, bias2, xA, B2, qb, kb, vb);
    vT_k<<<dim3(16, 12, 4), 256, 0, stream>>>(vb, Vtg);
    attn_k<<<dim3(16, 12, 4), 256, 0, stream>>>(qb, kb, Vtg, gate, biasTab, ctxb);
    out_gemm_k<<<dim3(6, 64), 256, 0, stream>>>(ctxb, Wall_b + 3 * 589824, bo, (float*)d_out);
}

// Round 11
// 224.939 us; speedup vs baseline: 1.0752x; 1.0752x over previous
//
#include <hip/hip_runtime.h>
#include <math.h>

// ---------- constants ----------
// B=4 T=1024 E=768 H=12 HD=64, NUM_BUCKETS=320, MAX_DIST=800
#define TT 1024
#define EE 768
#define HH 12

typedef __attribute__((ext_vector_type(8))) __bf16 bf16x8;
typedef __attribute__((ext_vector_type(4))) float f32x4;

__device__ __forceinline__ unsigned short f2b(float f) {
    unsigned int u = __float_as_uint(f);
    unsigned int r = (u + 0x7fffu + ((u >> 16) & 1u)) >> 16;
    return (unsigned short)r;
}

// async global->LDS, 16 bytes per lane; LDS dst must be wave-uniform base + lane*16
#define GLD16(gsrc, ldst) \
    __builtin_amdgcn_global_load_lds( \
        (const __attribute__((address_space(1))) unsigned int*)(gsrc), \
        (__attribute__((address_space(3))) unsigned int*)(ldst), 16, 0, 0)

// ================= setup: one kernel, branch-partitioned grid (1624 blocks) =========
// [0,1152): convert Wq|Wk|Wv|Wo fp32->bf16 (Wall_b)
// [1152,1260): W^T bf16 padded-LDS transpose (WT_all)
// [1260,1356): biasTab
// [1356,1368): bias2 = W@b + b, B2 = W@Bm (q pre-scaled 0.125)
// [1368,1624): hs rows -> hsb bf16 + gates + lora (16 rows/block)
__global__ __launch_bounds__(256)
void setup_k(const float* __restrict__ hs,
             const float* __restrict__ Wq, const float* __restrict__ Wk,
             const float* __restrict__ Wv, const float* __restrict__ Wo,
             const float* __restrict__ bq, const float* __restrict__ bk,
             const float* __restrict__ bv,
             const float* __restrict__ Aq, const float* __restrict__ Ak,
             const float* __restrict__ Av,
             const float* __restrict__ Bq, const float* __restrict__ Bk,
             const float* __restrict__ Bv,
             const float* __restrict__ Wg, const float* __restrict__ bg,
             const float* __restrict__ gru, const float* __restrict__ rel,
             unsigned short* __restrict__ Wall_b, unsigned short* __restrict__ WT_all,
             float* __restrict__ biasTab, float* __restrict__ bias2,
             float* __restrict__ B2,
             unsigned short* __restrict__ hsb, float* __restrict__ gate,
             float* __restrict__ xA) {
    __shared__ __align__(16) char smem[78080];
    const int bid = blockIdx.x, tid = threadIdx.x;

    if (bid < 1152) {                       // ---- weight convert ----
        size_t base = (size_t)bid * 2048 + tid * 8;
        int mat = (int)(base / 589824);
        size_t local = base % 589824;
        const float* S = mat == 0 ? Wq : (mat == 1 ? Wk : (mat == 2 ? Wv : Wo));
        float4 a = *(const float4*)&S[local];
        float4 c = *(const float4*)&S[local + 4];
        unsigned short hb[8] __attribute__((aligned(16)));
        hb[0] = f2b(a.x); hb[1] = f2b(a.y); hb[2] = f2b(a.z); hb[3] = f2b(a.w);
        hb[4] = f2b(c.x); hb[5] = f2b(c.y); hb[6] = f2b(c.z); hb[7] = f2b(c.w);
        *(uint4*)&Wall_b[base] = *(const uint4*)hb;
    } else if (bid < 1260) {                // ---- W^T (padded LDS, r7-proven) ----
        unsigned short* Ts = (unsigned short*)smem;   // [128][136]
        int v = bid - 1152;
        int mat = v / 36, tile = v % 36;
        int tr = tile / 6, tc = tile % 6;
        const float* S = mat == 0 ? Wq : (mat == 1 ? Wk : Wv);
        #pragma unroll
        for (int i = 0; i < 16; ++i) {
            int idx = i * 256 + tid;
            int row = idx >> 5, col4 = (idx & 31) * 4;
            float4 f = *(const float4*)&S[(size_t)(tr * 128 + row) * EE + tc * 128 + col4];
            Ts[(col4 + 0) * 136 + row] = f2b(f.x);
            Ts[(col4 + 1) * 136 + row] = f2b(f.y);
            Ts[(col4 + 2) * 136 + row] = f2b(f.z);
            Ts[(col4 + 3) * 136 + row] = f2b(f.w);
        }
        __syncthreads();
        unsigned short* dst = WT_all + (size_t)mat * 589824;
        #pragma unroll
        for (int i = 0; i < 8; ++i) {
            int idx = i * 256 + tid;
            int rr = idx >> 4, cg = (idx & 15) * 8;
            *(uint4*)&dst[(size_t)(tc * 128 + rr) * EE + tr * 128 + cg] =
                *(const uint4*)&Ts[rr * 136 + cg];
        }
    } else if (bid < 1356) {                // ---- biasTab ----
        int idx = (bid - 1260) * 256 + tid;
        if (idx < 2047 * 12) {
            int h = idx % 12;
            int rr = idx / 12;
            int relv = rr - 1023;
            int base = relv > 0 ? 160 : 0;
            int ar = relv < 0 ? -relv : relv;
            int bkt;
            if (ar < 80) bkt = base + ar;
            else {
                double lr = log((double)ar / 80.0);
                int large = 80 + (int)(lr / log(10.0) * 80.0);
                if (large > 159) large = 159;
                bkt = base + large;
            }
            biasTab[h * 2048 + rr] = rel[bkt * 12 + h];
        }
    } else if (bid < 1368) {                // ---- bias2 / B2 ----
        float* bvS = (float*)smem;           // 768
        float* BmS = bvS + 768;              // 1536
        int v = bid - 1356;                  // 0..11
        int sel = v / 4, nb = (v % 4) * 192;
        const float* W = sel == 0 ? Wq : (sel == 1 ? Wk : Wv);
        const float* bvec = sel == 0 ? bq : (sel == 1 ? bk : bv);
        const float* Bm = sel == 0 ? Bq : (sel == 1 ? Bk : Bv);
        for (int i = tid; i < 768; i += 256) bvS[i] = bvec[i];
        for (int i = tid; i < 1536; i += 256) BmS[i] = Bm[i];
        __syncthreads();
        if (tid < 192) {
            int n = nb + tid;
            const float* Wrow = W + (size_t)n * EE;
            float a0 = 0.f, a1 = 0.f, a2 = 0.f;
            for (int o = 0; o < EE; o += 4) {
                float4 w = *(const float4*)&Wrow[o];
                a0 += w.x * bvS[o] + w.y * bvS[o + 1] + w.z * bvS[o + 2] + w.w * bvS[o + 3];
                a1 += w.x * BmS[o * 2] + w.y * BmS[o * 2 + 2] + w.z * BmS[o * 2 + 4] + w.w * BmS[o * 2 + 6];
                a2 += w.x * BmS[o * 2 + 1] + w.y * BmS[o * 2 + 3] + w.z * BmS[o * 2 + 5] + w.w * BmS[o * 2 + 7];
            }
            float sc = (sel == 0) ? 0.125f : 1.0f;
            bias2[sel * 768 + n] = (a0 + bvS[n]) * sc;
            B2[sel * 1536 + n * 2 + 0] = a1 * sc;
            B2[sel * 1536 + n * 2 + 1] = a2 * sc;
        }
    } else {                                // ---- hs rows: hsb + gates + lora ----
        float* rowF = (float*)smem;          // 16*772
        float* AS   = rowF + 16 * 772;       // 6*768
        float* WgS  = AS + 6 * 768;          // 8*68
        float* gpS  = WgS + 8 * 68;          // 16*100
        float* redS = gpS + 16 * 100;        // 4*96
        float* bgS  = redS + 4 * 96;         // 8
        float* gcS  = bgS + 8;               // 12
        const int m0 = (bid - 1368) * 16;

        for (int i = tid; i < 512; i += 256) WgS[(i >> 6) * 68 + (i & 63)] = Wg[i];
        for (int i = tid; i < 1152; i += 256) {
            int which = i / 192, c4 = (i % 192) * 4;
            const float* src = (which < 2 ? Aq : (which < 4 ? Ak : Av)) + (which & 1) * 768 + c4;
            float4 f = *(const float4*)src;
            AS[which * 768 + c4 + 0] = f.x; AS[which * 768 + c4 + 1] = f.y;
            AS[which * 768 + c4 + 2] = f.z; AS[which * 768 + c4 + 3] = f.w;
        }
        if (tid < 8)  bgS[tid] = bg[tid];
        if (tid < 12) gcS[tid] = gru[tid];
        #pragma unroll
        for (int i = 0; i < 12; ++i) {
            int idx = i * 256 + tid;                 // [0,3072)
            int row = idx / 192, c4 = (idx % 192) * 4;
            float4 f = *(const float4*)&hs[(size_t)(m0 + row) * EE + c4];
            rowF[row * 772 + c4 + 0] = f.x; rowF[row * 772 + c4 + 1] = f.y;
            rowF[row * 772 + c4 + 2] = f.z; rowF[row * 772 + c4 + 3] = f.w;
            unsigned int lo = (unsigned int)f2b(f.x) | ((unsigned int)f2b(f.y) << 16);
            unsigned int hi = (unsigned int)f2b(f.z) | ((unsigned int)f2b(f.w) << 16);
            uint2 p; p.x = lo; p.y = hi;
            *(uint2*)&hsb[(size_t)(m0 + row) * EE + c4] = p;
        }
        __syncthreads();
        #pragma unroll
        for (int j = 0; j < 6; ++j) {
            int idx = j * 256 + tid;                 // [0,1536)
            int row = idx & 15, q = idx >> 4;
            int h = q % 12, e = q / 12;
            const float* rp = &rowF[row * 772 + h * 64];
            const float* wp = &WgS[e * 68];
            float a = 0.f;
            #pragma unroll 16
            for (int d = 0; d < 64; ++d) a += rp[d] * wp[d];
            gpS[row * 100 + h * 8 + e] = a;
        }
        {
            int row = tid & 15, seg = tid >> 4;
            float s[6] = {0.f, 0.f, 0.f, 0.f, 0.f, 0.f};
            #pragma unroll 8
            for (int j = 0; j < 48; ++j) {
                int e = seg * 48 + j;
                float xv = rowF[row * 772 + e];
                s[0] += xv * AS[e];            s[1] += xv * AS[768 + e];
                s[2] += xv * AS[1536 + e];     s[3] += xv * AS[2304 + e];
                s[4] += xv * AS[3072 + e];     s[5] += xv * AS[3840 + e];
            }
            #pragma unroll
            for (int i = 0; i < 6; ++i) {
                s[i] += __shfl_xor(s[i], 16, 64);
                s[i] += __shfl_xor(s[i], 32, 64);
            }
            int lane = tid & 63, w = tid >> 6;
            if ((lane >> 4) == 0)
                #pragma unroll
                for (int i = 0; i < 6; ++i) redS[w * 96 + row * 6 + i] = s[i];
        }
        __syncthreads();
        if (tid < 96) {
            int row = tid / 6, i = tid % 6;
            float v = redS[row * 6 + i] + redS[96 + row * 6 + i] +
                      redS[192 + row * 6 + i] + redS[288 + row * 6 + i];
            int sel = i >> 1, r = i & 1;
            xA[sel * 8192 + (size_t)(m0 + row) * 2 + r] = v;
        }
        if (tid < 192) {
            int row = tid / 12, h = tid % 12;
            const float* gp = &gpS[row * 100 + h * 8];
            float s0 = gp[0] + gp[1] + gp[2] + gp[3] + bgS[0] + bgS[1] + bgS[2] + bgS[3];
            float s1 = gp[4] + gp[5] + gp[6] + gp[7] + bgS[4] + bgS[5] + bgS[6] + bgS[7];
            float ga = 1.f / (1.f + __expf(-s0));
            float gb = 1.f / (1.f + __expf(-s1));
            int m = m0 + row;
            int b = m >> 10, tp = m & 1023;
            gate[((size_t)b * HH + h) * TT + tp] = ga * (gb * gcS[h] - 1.0f) + 2.0f;
        }
    }
}

// ---------- W2 = W@W (bf16), 108 blocks of 128x128; q pre-scaled 0.125 ----------
__global__ __launch_bounds__(256, 3)
void wgemm_k(const unsigned short* __restrict__ Wall_b,
             const unsigned short* __restrict__ WT_all,
             unsigned short* __restrict__ W2_all) {
    __shared__ unsigned short At[128 * 32];
    __shared__ unsigned short Bt[128 * 32];
    const int tid = threadIdx.x;
    const int bxx = blockIdx.x;
    const int sel = bxx / 36, tile = bxx % 36;
    const int row0 = (tile / 6) * 128, col0 = (tile % 6) * 128;
    const unsigned short* A = Wall_b + (size_t)sel * 589824;
    const unsigned short* Bw = WT_all + (size_t)sel * 589824;

    const int lane = tid & 63, wv = tid >> 6;
    const int wm = (wv & 1) * 64, wn = (wv >> 1) * 64;
    const int l15 = lane & 15, g8 = (lane >> 4) * 8;
    const int lr = lane >> 2, lc = (lane & 3) * 8;
    const int c0 = wv * 2, c1 = wv * 2 + 1;
    const unsigned short* Abase0 = A + (size_t)(row0 + c0 * 16 + lr) * EE + lc;
    const unsigned short* Abase1 = A + (size_t)(row0 + c1 * 16 + lr) * EE + lc;
    const unsigned short* Bbase0 = Bw + (size_t)(col0 + c0 * 16 + lr) * EE + lc;
    const unsigned short* Bbase1 = Bw + (size_t)(col0 + c1 * 16 + lr) * EE + lc;

    f32x4 zero4 = {0.f, 0.f, 0.f, 0.f};
    f32x4 acc[4][4];
    #pragma unroll
    for (int i = 0; i < 4; ++i)
        #pragma unroll
        for (int j = 0; j < 4; ++j) acc[i][j] = zero4;

    for (int kt = 0; kt < 768; kt += 32) {
        GLD16(Abase0 + kt, &At[c0 * 512]);
        GLD16(Abase1 + kt, &At[c1 * 512]);
        GLD16(Bbase0 + kt, &Bt[c0 * 512]);
        GLD16(Bbase1 + kt, &Bt[c1 * 512]);
        __syncthreads();
        bf16x8 af[4], bf[4];
        #pragma unroll
        for (int mt = 0; mt < 4; ++mt) af[mt] = *(const bf16x8*)&At[(wm + mt * 16 + l15) * 32 + g8];
        #pragma unroll
        for (int nt = 0; nt < 4; ++nt) bf[nt] = *(const bf16x8*)&Bt[(wn + nt * 16 + l15) * 32 + g8];
        #pragma unroll
        for (int mt = 0; mt < 4; ++mt)
            #pragma unroll
            for (int nt = 0; nt < 4; ++nt)
                acc[mt][nt] = __builtin_amdgcn_mfma_f32_16x16x32_bf16(af[mt], bf[nt], acc[mt][nt], 0, 0, 0);
        __syncthreads();
    }
    unsigned short* out = W2_all + (size_t)sel * 589824;
    const float sc = (sel == 0) ? 0.125f : 1.0f;
    const int g4 = (lane >> 4) * 4;
    #pragma unroll
    for (int mt = 0; mt < 4; ++mt)
        #pragma unroll
        for (int r = 0; r < 4; ++r) {
            int grow = row0 + wm + mt * 16 + g4 + r;
            #pragma unroll
            for (int nt = 0; nt < 4; ++nt) {
                int ncol = col0 + wn + nt * 16 + l15;
                out[(size_t)grow * EE + ncol] = f2b(acc[mt][nt][r] * sc);
            }
        }
}

// ---------- fused QKV GEMM: 128x128 tiles; V written pre-transposed via LDS ----------
__global__ __launch_bounds__(256, 3)
void qkv_gemm_k(const unsigned short* __restrict__ Aall,
                const unsigned short* __restrict__ W2_all,
                const float* __restrict__ bias2,
                const float* __restrict__ xA, const float* __restrict__ B2,
                unsigned short* __restrict__ qb, unsigned short* __restrict__ kb,
                unsigned short* __restrict__ Vtg) {
    __shared__ unsigned short At[128 * 32];
    __shared__ unsigned short Bt[128 * 32];
    __shared__ unsigned short Tv[64 * 136];   // V-transpose half-tile (sel==2 only)
    const int tid = threadIdx.x;
    const int bx = blockIdx.x, by = blockIdx.y;
    const int sel = bx / 6;
    const int col0 = (bx % 6) * 128, row0 = by * 128;
    const unsigned short* Wb = W2_all + (size_t)sel * 589824;
    const float* bias = bias2 + sel * 768;

    const int lane = tid & 63, wv = tid >> 6;
    const int wm = (wv & 1) * 64, wn = (wv >> 1) * 64;
    const int l15 = lane & 15, g8 = (lane >> 4) * 8;
    const int lr = lane >> 2, lc = (lane & 3) * 8;
    const int c0 = wv * 2, c1 = wv * 2 + 1;
    const unsigned short* Abase0 = Aall + (size_t)(row0 + c0 * 16 + lr) * EE + lc;
    const unsigned short* Abase1 = Aall + (size_t)(row0 + c1 * 16 + lr) * EE + lc;
    const unsigned short* Bbase0 = Wb + (size_t)(col0 + c0 * 16 + lr) * EE + lc;
    const unsigned short* Bbase1 = Wb + (size_t)(col0 + c1 * 16 + lr) * EE + lc;

    f32x4 zero4 = {0.f, 0.f, 0.f, 0.f};
    f32x4 acc[4][4];
    #pragma unroll
    for (int i = 0; i < 4; ++i)
        #pragma unroll
        for (int j = 0; j < 4; ++j) acc[i][j] = zero4;

    for (int kt = 0; kt < 768; kt += 32) {
        GLD16(Abase0 + kt, &At[c0 * 512]);
        GLD16(Abase1 + kt, &At[c1 * 512]);
        GLD16(Bbase0 + kt, &Bt[c0 * 512]);
        GLD16(Bbase1 + kt, &Bt[c1 * 512]);
        __syncthreads();
        bf16x8 af[4], bf[4];
        #pragma unroll
        for (int mt = 0; mt < 4; ++mt) af[mt] = *(const bf16x8*)&At[(wm + mt * 16 + l15) * 32 + g8];
        #pragma unroll
        for (int nt = 0; nt < 4; ++nt) bf[nt] = *(const bf16x8*)&Bt[(wn + nt * 16 + l15) * 32 + g8];
        #pragma unroll
        for (int mt = 0; mt < 4; ++mt)
            #pragma unroll
            for (int nt = 0; nt < 4; ++nt)
                acc[mt][nt] = __builtin_amdgcn_mfma_f32_16x16x32_bf16(af[mt], bf[nt], acc[mt][nt], 0, 0, 0);
        __syncthreads();
    }

    const float* Lbase = xA + sel * 8192;
    const float* B2s   = B2 + sel * 1536;
    const int g4 = (lane >> 4) * 4;
    if (sel < 2) {
        unsigned short* dst = sel == 0 ? qb : kb;
        #pragma unroll
        for (int mt = 0; mt < 4; ++mt) {
            #pragma unroll
            for (int r = 0; r < 4; ++r) {
                size_t grow = (size_t)row0 + wm + mt * 16 + g4 + r;
                float l0 = Lbase[grow * 2], l1 = Lbase[grow * 2 + 1];
                #pragma unroll
                for (int nt = 0; nt < 4; ++nt) {
                    int ncol = col0 + wn + nt * 16 + l15;
                    float c = acc[mt][nt][r] + bias[ncol]
                              + 0.5f * (l0 * B2s[ncol * 2] + l1 * B2s[ncol * 2 + 1]);
                    dst[grow * EE + ncol] = f2b(c);
                }
            }
        }
    } else {
        // V: transpose through Tv, write Vtg[((b*12+h)*64+d)*1024 + t] coalesced
        const int b = row0 >> 10, t0 = row0 & 1023;
        #pragma unroll
        for (int p = 0; p < 2; ++p) {
            __syncthreads();                       // Tv free
            if ((wv >> 1) == p) {                  // waves whose wn == p*64
                #pragma unroll
                for (int mt = 0; mt < 4; ++mt) {
                    #pragma unroll
                    for (int r = 0; r < 4; ++r) {
                        int rloc = wm + mt * 16 + g4 + r;
                        size_t grow = (size_t)row0 + rloc;
                        float l0 = Lbase[grow * 2], l1 = Lbase[grow * 2 + 1];
                        #pragma unroll
                        for (int nt = 0; nt < 4; ++nt) {
                            int c = nt * 16 + l15;           // col within half
                            int ncol = col0 + p * 64 + c;
                            float cv = acc[mt][nt][r] + bias[ncol]
                                     + 0.5f * (l0 * B2s[ncol * 2] + l1 * B2s[ncol * 2 + 1]);
                            Tv[c * 136 + rloc] = f2b(cv);
                        }
                    }
                }
            }
            __syncthreads();                       // Tv filled (64 cols x 128 rows)
            int c = tid >> 2, s = (tid & 3) * 32;
            int colg = col0 + p * 64 + c;
            int h = colg >> 6, d = colg & 63;
            unsigned short* vp = Vtg + (((size_t)b * HH + h) * 64 + d) * TT + t0 + s;
            #pragma unroll
            for (int j = 0; j < 4; ++j)
                *(uint4*)(vp + j * 8) = *(const uint4*)&Tv[c * 136 + s + j * 8];
        }
    }
}

// ---------- MFMA flash attention (r9-proven): bias via L2, K/V prefetch, 4 blocks/CU ----------
__global__ __launch_bounds__(256, 4)
void attn_k(const unsigned short* __restrict__ qb, const unsigned short* __restrict__ kb,
            const unsigned short* __restrict__ Vtg, const float* __restrict__ gate,
            const float* __restrict__ biasTab, unsigned short* __restrict__ ctx) {
    __shared__ unsigned short Qs[64 * 72];
    __shared__ unsigned short Ks[64 * 72];
    __shared__ unsigned short Vt[64 * 72];
    __shared__ unsigned short Ps[64 * 72];
    const int tid = threadIdx.x;
    const int qt = blockIdx.x, h = blockIdx.y, b = blockIdx.z;

    const int srow = tid >> 2, scol = (tid & 3) * 16;
    {
        const unsigned short* qp = qb + ((size_t)(b * TT + qt * 64 + srow)) * EE + h * 64 + scol;
        *(uint4*)&Qs[srow * 72 + scol]     = *(const uint4*)qp;
        *(uint4*)&Qs[srow * 72 + scol + 8] = *(const uint4*)(qp + 8);
    }
    const int lane = tid & 63, wv = tid >> 6;
    const int m0 = wv * 16;
    const int l15 = lane & 15, g = lane >> 4;

    float li[4];
    f32x4 zero4 = {0.f, 0.f, 0.f, 0.f};
    f32x4 oa[4];
    #pragma unroll
    for (int r = 0; r < 4; ++r) li[r] = 0.f;
    #pragma unroll
    for (int nt = 0; nt < 4; ++nt) oa[nt] = zero4;
    float gv[4];
    #pragma unroll
    for (int r = 0; r < 4; ++r)
        gv[r] = gate[((size_t)(b * HH + h)) * TT + qt * 64 + m0 + 4 * g + r];

    const unsigned short* kpbase = kb + ((size_t)(b * TT + srow)) * EE + h * 64 + scol;
    const unsigned short* vpbase = Vtg + ((size_t)(b * HH + h) * 64 + srow) * TT + scol;
    const float* btab = biasTab + h * 2048 + 1023 + l15 - qt * 64 - m0 - 4 * g;

    uint4 kr0 = *(const uint4*)kpbase;
    uint4 kr1 = *(const uint4*)(kpbase + 8);
    uint4 vr0 = *(const uint4*)vpbase;
    uint4 vr1 = *(const uint4*)(vpbase + 8);

    for (int kt = 0; kt < 16; ++kt) {
        __syncthreads();
        *(uint4*)&Ks[srow * 72 + scol]     = kr0;
        *(uint4*)&Ks[srow * 72 + scol + 8] = kr1;
        *(uint4*)&Vt[srow * 72 + scol]     = vr0;
        *(uint4*)&Vt[srow * 72 + scol + 8] = vr1;
        __syncthreads();
        if (kt < 15) {
            const unsigned short* kp = kpbase + (size_t)(kt + 1) * 64 * EE;
            kr0 = *(const uint4*)kp;
            kr1 = *(const uint4*)(kp + 8);
            const unsigned short* vp = vpbase + (kt + 1) * 64;
            vr0 = *(const uint4*)vp;
            vr1 = *(const uint4*)(vp + 8);
        }
        f32x4 sa[4];
        #pragma unroll
        for (int nt = 0; nt < 4; ++nt) sa[nt] = zero4;
        bf16x8 aq0 = *(const bf16x8*)&Qs[(m0 + l15) * 72 + g * 8];
        bf16x8 aq1 = *(const bf16x8*)&Qs[(m0 + l15) * 72 + 32 + g * 8];
        #pragma unroll
        for (int nt = 0; nt < 4; ++nt) {
            bf16x8 bk0 = *(const bf16x8*)&Ks[(nt * 16 + l15) * 72 + g * 8];
            bf16x8 bk1 = *(const bf16x8*)&Ks[(nt * 16 + l15) * 72 + 32 + g * 8];
            sa[nt] = __builtin_amdgcn_mfma_f32_16x16x32_bf16(aq0, bk0, sa[nt], 0, 0, 0);
            sa[nt] = __builtin_amdgcn_mfma_f32_16x16x32_bf16(aq1, bk1, sa[nt], 0, 0, 0);
        }
        #pragma unroll
        for (int nt = 0; nt < 4; ++nt) {
            const float* bt = btab + kt * 64 + nt * 16;
            #pragma unroll
            for (int r = 0; r < 4; ++r) {
                float e = __expf(fmaf(gv[r], bt[-r], sa[nt][r]));
                li[r] += e;
                Ps[(m0 + 4 * g + r) * 72 + nt * 16 + l15] = f2b(e);
            }
        }
        bf16x8 ap0 = *(const bf16x8*)&Ps[(m0 + l15) * 72 + g * 8];
        bf16x8 ap1 = *(const bf16x8*)&Ps[(m0 + l15) * 72 + 32 + g * 8];
        #pragma unroll
        for (int nt = 0; nt < 4; ++nt) {
            bf16x8 bv0 = *(const bf16x8*)&Vt[(nt * 16 + l15) * 72 + g * 8];
            bf16x8 bv1 = *(const bf16x8*)&Vt[(nt * 16 + l15) * 72 + 32 + g * 8];
            oa[nt] = __builtin_amdgcn_mfma_f32_16x16x32_bf16(ap0, bv0, oa[nt], 0, 0, 0);
            oa[nt] = __builtin_amdgcn_mfma_f32_16x16x32_bf16(ap1, bv1, oa[nt], 0, 0, 0);
        }
    }
    __syncthreads();
    #pragma unroll
    for (int r = 0; r < 4; ++r) {
        #pragma unroll
        for (int msk = 1; msk < 16; msk <<= 1)
            li[r] += __shfl_xor(li[r], msk, 16);
    }
    #pragma unroll
    for (int nt = 0; nt < 4; ++nt)
        #pragma unroll
        for (int r = 0; r < 4; ++r)
            Ks[(m0 + 4 * g + r) * 72 + nt * 16 + l15] = f2b(oa[nt][r] / li[r]);
    __syncthreads();
    {
        unsigned short* cp = ctx + ((size_t)(b * TT + qt * 64 + srow)) * EE + h * 64 + scol;
        *(uint4*)cp       = *(const uint4*)&Ks[srow * 72 + scol];
        *(uint4*)(cp + 8) = *(const uint4*)&Ks[srow * 72 + scol + 8];
    }
}

// ---------- output GEMM (r9-proven): 64x128 tiles, grid 384 ----------
__global__ __launch_bounds__(256, 4)
void out_gemm_k(const unsigned short* __restrict__ Aall,
                const unsigned short* __restrict__ Wob,
                const float* __restrict__ bo, float* __restrict__ outf) {
    __shared__ unsigned short At[64 * 32];
    __shared__ unsigned short Bt[128 * 32];
    const int tid = threadIdx.x;
    const int col0 = blockIdx.x * 128, row0 = blockIdx.y * 64;

    const int lane = tid & 63, wv = tid >> 6;
    const int wm = (wv & 1) * 32, wn = (wv >> 1) * 64;
    const int l15 = lane & 15, g8 = (lane >> 4) * 8;
    const int lr = lane >> 2, lc = (lane & 3) * 8;
    const int c0 = wv * 2, c1 = wv * 2 + 1;
    const unsigned short* Abase  = Aall + (size_t)(row0 + wv * 16 + lr) * EE + lc;
    const unsigned short* Bbase0 = Wob + (size_t)(col0 + c0 * 16 + lr) * EE + lc;
    const unsigned short* Bbase1 = Wob + (size_t)(col0 + c1 * 16 + lr) * EE + lc;

    f32x4 zero4 = {0.f, 0.f, 0.f, 0.f};
    f32x4 acc[2][4];
    #pragma unroll
    for (int i = 0; i < 2; ++i)
        #pragma unroll
        for (int j = 0; j < 4; ++j) acc[i][j] = zero4;

    for (int kt = 0; kt < 768; kt += 32) {
        GLD16(Abase + kt, &At[wv * 512]);
        GLD16(Bbase0 + kt, &Bt[c0 * 512]);
        GLD16(Bbase1 + kt, &Bt[c1 * 512]);
        __syncthreads();
        bf16x8 af[2], bf[4];
        #pragma unroll
        for (int mt = 0; mt < 2; ++mt) af[mt] = *(const bf16x8*)&At[(wm + mt * 16 + l15) * 32 + g8];
        #pragma unroll
        for (int nt = 0; nt < 4; ++nt) bf[nt] = *(const bf16x8*)&Bt[(wn + nt * 16 + l15) * 32 + g8];
        #pragma unroll
        for (int mt = 0; mt < 2; ++mt)
            #pragma unroll
            for (int nt = 0; nt < 4; ++nt)
                acc[mt][nt] = __builtin_amdgcn_mfma_f32_16x16x32_bf16(af[mt], bf[nt], acc[mt][nt], 0, 0, 0);
        __syncthreads();
    }
    const int g4 = (lane >> 4) * 4;
    #pragma unroll
    for (int mt = 0; mt < 2; ++mt)
        #pragma unroll
        for (int r = 0; r < 4; ++r) {
            size_t grow = (size_t)row0 + wm + mt * 16 + g4 + r;
            #pragma unroll
            for (int nt = 0; nt < 4; ++nt) {
                int ncol = col0 + wn + nt * 16 + l15;
                outf[grow * EE + ncol] = acc[mt][nt][r] + bo[ncol];
            }
        }
}

// ---------- launch ----------
extern "C" void kernel_launch(void* const* d_in, const int* in_sizes, int n_in,
                              void* d_out, int out_size, void* d_ws, size_t ws_size,
                              hipStream_t stream) {
    const float* hs  = (const float*)d_in[0];
    const float* Wq  = (const float*)d_in[1];
    const float* bq  = (const float*)d_in[2];
    const float* Wk  = (const float*)d_in[3];
    const float* bk  = (const float*)d_in[4];
    const float* Wv  = (const float*)d_in[5];
    const float* bv  = (const float*)d_in[6];
    const float* Aq  = (const float*)d_in[7];
    const float* Bq  = (const float*)d_in[8];
    const float* Ak  = (const float*)d_in[9];
    const float* Bk  = (const float*)d_in[10];
    const float* Av  = (const float*)d_in[11];
    const float* Bv  = (const float*)d_in[12];
    const float* Wo  = (const float*)d_in[13];
    const float* bo  = (const float*)d_in[14];
    const float* Wg  = (const float*)d_in[15];
    const float* bg  = (const float*)d_in[16];
    const float* gru = (const float*)d_in[17];
    const float* rel = (const float*)d_in[18];

    float* ws = (float*)d_ws;
    float* gate    = ws;                    // 49152
    float* biasTab = gate + 49152;          // 24576
    float* xA      = biasTab + 24576;       // 24576
    float* bias2   = xA + 24576;            // 2304
    float* B2      = bias2 + 2304;          // 4608
    unsigned short* hsb    = (unsigned short*)(B2 + 4608);
    unsigned short* Wall_b = hsb + 3145728;          // 4 x 589824 (Wq,Wk,Wv,Wo)
    unsigned short* WT_all = Wall_b + 4 * 589824;    // 3 x 589824
    unsigned short* W2_all = WT_all + 3 * 589824;    // 3 x 589824
    unsigned short* qb     = W2_all + 3 * 589824;
    unsigned short* kb     = qb + 3145728;
    unsigned short* Vtg    = kb + 3145728;
    unsigned short* ctxb   = Vtg + 3145728;

    setup_k<<<1624, 256, 0, stream>>>(hs, Wq, Wk, Wv, Wo, bq, bk, bv,
                                      Aq, Ak, Av, Bq, Bk, Bv, Wg, bg, gru, rel,
                                      Wall_b, WT_all, biasTab, bias2, B2,
                                      hsb, gate, xA);
    wgemm_k<<<108, 256, 0, stream>>>(Wall_b, WT_all, W2_all);
    qkv_gemm_k<<<dim3(18, 32), 256, 0, stream>>>(hsb, W2_all, bias2, xA, B2, qb, kb, Vtg);
    attn_k<<<dim3(16, 12, 4), 256, 0, stream>>>(qb, kb, Vtg, gate, biasTab, ctxb);
    out_gemm_k<<<dim3(6, 64), 256, 0, stream>>>(ctxb, Wall_b + 3 * 589824, bo, (float*)d_out);
}